// Round 5
// baseline (419.548 us; speedup 1.0000x reference)
//
#include <hip/hip_runtime.h>
#include <hip/hip_bf16.h>
#include <math.h>

// Problem constants (fixed by setup_inputs: B=4, L=2048)
#define BB      4
#define LL      2048
#define KNB     30
#define NRES    (BB*LL)          // 8192
#define NEDGE   (NRES*KNB)       // 245760
#define EDGE_IN 416              // 16 pos + 25*16 RBF = 13 * 32
#define KT      13               // K-tiles of 32
#define ME      32               // edges per block in edge kernel
#define ASTRIDE 424              // A-tile row stride in fp16 (848 B, 16B-aligned, 2-way banks)

typedef __attribute__((ext_vector_type(8))) _Float16 half8;
typedef __attribute__((ext_vector_type(4))) float floatx4;

__device__ __constant__ int d_PA[25] = {0,1,2,3,4,0,0,0,0,1,1,1,4,4,3,1,2,3,4,2,3,4,2,3,2};
__device__ __constant__ int d_PB[25] = {0,1,2,3,4,1,2,3,4,2,3,4,2,3,2,0,0,0,0,1,1,1,4,4,3};

__device__ __forceinline__ unsigned short f2h_bits(float x) {
    _Float16 h = (_Float16)x;
    union { _Float16 h; unsigned short u; } v; v.h = h;
    return v.u;
}
__device__ __forceinline__ unsigned pack2h(float a, float b) {
    return (unsigned)f2h_bits(a) | ((unsigned)f2h_bits(b) << 16);
}

// 64-lane lexicographic (value, index) min — all lanes converge to the min.
__device__ __forceinline__ void lexmin64(float& v, int& j) {
#pragma unroll
    for (int off = 1; off < 64; off <<= 1) {
        float ov = __shfl_xor(v, off);
        int   oj = __shfl_xor(j, off);
        if (ov < v || (ov == v && oj < j)) { v = ov; j = oj; }
    }
}

// ---------------------------------------------------------------------------
// Kernel 1: per-residue atom construction.  atoms[r][5][3] = [Ca,N,C,O,Cb]
// ---------------------------------------------------------------------------
__global__ __launch_bounds__(256) void atoms_kernel(const float* __restrict__ X,
                                                    float* __restrict__ atoms) {
    int r = blockIdx.x * blockDim.x + threadIdx.x;
    if (r >= NRES) return;
    const float* xr = X + (size_t)r * 12;
    float Nx = xr[0],  Ny = xr[1],  Nz = xr[2];
    float Ax = xr[3],  Ay = xr[4],  Az = xr[5];   // Ca
    float Cx = xr[6],  Cy = xr[7],  Cz = xr[8];
    float Ox = xr[9],  Oy = xr[10], Oz = xr[11];
    float bx = Ax - Nx, by = Ay - Ny, bz = Az - Nz;
    float cx = Cx - Ax, cy = Cy - Ay, cz = Cz - Az;
    float ax = by * cz - bz * cy;
    float ay = bz * cx - bx * cz;
    float az = bx * cy - by * cx;
    float Cbx = -0.58273431f * ax + 0.56802827f * bx - 0.54067466f * cx + Ax;
    float Cby = -0.58273431f * ay + 0.56802827f * by - 0.54067466f * cy + Ay;
    float Cbz = -0.58273431f * az + 0.56802827f * bz - 0.54067466f * cz + Az;
    float* o = atoms + (size_t)r * 15;
    o[0]  = Ax;  o[1]  = Ay;  o[2]  = Az;
    o[3]  = Nx;  o[4]  = Ny;  o[5]  = Nz;
    o[6]  = Cx;  o[7]  = Cy;  o[8]  = Cz;
    o[9]  = Ox;  o[10] = Oy;  o[11] = Oz;
    o[12] = Cbx; o[13] = Cby; o[14] = Cbz;
}

// ---------------------------------------------------------------------------
// Kernel 2: top-K — ONE WAVE PER RESIDUE, tournament select.
// 32 groups of 64; group minima built during the distance pass (free wave
// reduce per init step).  Each round: 6-shuffle reduce over group minima,
// invalidate winner, rescan ONLY its 64-element group (1 ds_read).
// Lex (value, lower index) order == jax.lax.top_k(-D) semantics; distances
// bit-exact vs the fp32 numpy pipeline (contract off).
// ---------------------------------------------------------------------------
__global__ __launch_bounds__(256) void topk_kernel(const float* __restrict__ X,
                                                   const float* __restrict__ mask,
                                                   int* __restrict__ E_idx) {
#pragma clang fp contract(off)
    __shared__ float Dv[4][LL];     // 32 KB

    int t    = threadIdx.x;
    int wid  = t >> 6;
    int lane = t & 63;
    int bi   = blockIdx.x * 4 + wid;      // residue
    int b    = bi >> 11;

    const float* cai = X + ((size_t)bi * 4 + 1) * 3;
    float cx = cai[0], cy = cai[1], cz = cai[2];
    float mi = mask[bi];
    float* dv = Dv[wid];

    float Dj[32], m2r[32];
    float lmax = 0.0f;
#pragma unroll
    for (int i = 0; i < 32; i++) {
        int j = i * 64 + lane;
        const float* cj = X + (((size_t)((b << 11) + j)) * 4 + 1) * 3;
        float dx = cx - cj[0], dy = cy - cj[1], dz = cz - cj[2];
        float ssq = ((dx * dx + dy * dy) + dz * dz) + 1e-6f;
        float m2  = mask[(b << 11) + j] * mi;
        Dj[i]  = m2 * sqrtf(ssq);
        m2r[i] = m2;
        lmax = fmaxf(lmax, Dj[i]);
    }
#pragma unroll
    for (int off = 1; off < 64; off <<= 1) lmax = fmaxf(lmax, __shfl_xor(lmax, off));

    // adjusted distances -> LDS, group minima -> lane i holds group i's (v,j)
    float gv = 3.4e38f;
    int   gj = 0x7fffffff;
#pragma unroll
    for (int i = 0; i < 32; i++) {
        int j = i * 64 + lane;
        float v = Dj[i] + (1.0f - m2r[i]) * lmax;   // exact no-op when mask==1
        dv[j] = v;
        float bv = v; int bj = j;
        lexmin64(bv, bj);
        if (lane == i) { gv = bv; gj = bj; }        // lanes 32..63 keep +inf
    }

    int* eout = E_idx + (size_t)bi * KNB;
    for (int k = 0; k < KNB; k++) {
        float bv = gv; int bj = gj;
        lexmin64(bv, bj);                           // global lex-min
        if (lane == 0) eout[k] = bj;
        int g = bj >> 6;
        if (lane == (bj & 63)) dv[bj] = 3.4e38f;    // invalidate (same-lane RAW below)
        float nv = dv[g * 64 + lane];               // rescan winner's group only
        int   nj = g * 64 + lane;
        lexmin64(nv, nj);
        if (lane == g) { gv = nv; gj = nj; }
    }
}

// ---------------------------------------------------------------------------
// Kernel 2.5: pre-swizzle W_edge (fp32 [416][128]) into SPLIT fp16 B-fragment
// order: Wh = fp16(W), Wl = fp16(W - Wh).  Layout [kk][nt][lane] of half8:
// element holds W[k = kk*32 + (lane>>4)*8 + j][n = nt*16 + (lane&15)].
// ---------------------------------------------------------------------------
__global__ __launch_bounds__(256) void wprep_kernel(const float* __restrict__ W_edge,
                                                    half8* __restrict__ Wfh,
                                                    half8* __restrict__ Wfl) {
    int t = blockIdx.x * blockDim.x + threadIdx.x;
    if (t >= KT * 8 * 64) return;
    int kk   = t >> 9;
    int rem  = t & 511;
    int nt   = rem >> 6;
    int lane = rem & 63;
    int n  = nt * 16 + (lane & 15);
    int kb = kk * 32 + (lane >> 4) * 8;
    half8 vh, vl;
#pragma unroll
    for (int j = 0; j < 8; j++) {
        float w = W_edge[(size_t)(kb + j) * 128 + n];
        _Float16 wh = (_Float16)w;
        vh[j] = wh;
        vl[j] = (_Float16)(w - (float)wh);
    }
    Wfh[t] = vh;
    Wfl[t] = vl;
}

// ---------------------------------------------------------------------------
// Kernel 3: edge featurization (SPLIT fp16 A-tile) + 3-term MFMA GEMM + LN.
// 512 threads = 8 waves over a 32-edge x 128-feature tile:
//   wave w: edge strip (w>>2)*16, feature quad cq = w&3 (n in [cq*32, cq*32+32)).
// Same 59 KB LDS as R4's 256-thread version now feeds 8 waves -> 4 waves/SIMD
// (was 2), hiding the L2 B-fetch latency; per-block B traffic halves.
// E = Ah*Wh + Al*Wh + Ah*Wl (fp32 accum) — effective fp32 GEMM precision.
// ---------------------------------------------------------------------------
__global__ __launch_bounds__(512) void edge_kernel(const float* __restrict__ atoms,
                                                   const int* __restrict__ E_idx,
                                                   const int* __restrict__ resi,
                                                   const float* __restrict__ W_pos,
                                                   const float* __restrict__ b_pos,
                                                   const half8* __restrict__ Wfh,
                                                   const half8* __restrict__ Wfl,
                                                   const float* __restrict__ gamma,
                                                   const float* __restrict__ beta,
                                                   float* __restrict__ out) {
    __shared__ _Float16 Ah[ME * ASTRIDE];          // 27136 B
    __shared__ _Float16 Al[ME * ASTRIDE];          // 27136 B
    __shared__ float Dl[ME][26];                   //  3328 B
    __shared__ float redS[4][ME];                  //   512 B  (sum partials)
    __shared__ float redT[4][ME];                  //   512 B  (sumsq partials)
    __shared__ int   s_gi[ME], s_gj[ME], s_d[ME];  //   384 B

    int t  = threadIdx.x;
    int e0 = blockIdx.x * ME;

    if (t < ME) {
        int e  = e0 + t;
        int gi = e / KNB;
        int k  = e - gi * KNB;
        int b  = gi >> 11;
        int j  = E_idx[(size_t)gi * KNB + k];
        s_gi[t] = gi;
        s_gj[t] = (b << 11) + j;
        int off = resi[gi] - resi[(b << 11) + j];
        int d = off + 32;
        s_d[t] = d < 0 ? 0 : (d > 64 ? 64 : d);
    }
    __syncthreads();

    for (int idx = t; idx < ME * 25; idx += 512) {
        int e = idx / 25, p = idx - e * 25;
        const float* Ar = atoms + (size_t)s_gi[e] * 15 + d_PA[p] * 3;
        const float* Br = atoms + (size_t)s_gj[e] * 15 + d_PB[p] * 3;
        float dx = Ar[0] - Br[0];
        float dy = Ar[1] - Br[1];
        float dz = Ar[2] - Br[2];
        Dl[e][p] = sqrtf(dx * dx + dy * dy + dz * dz + 1e-6f);
    }
    __syncthreads();

    // --- fill split fp16 A-tile: 16 threads per edge, 26-feature chunks ---
    {
        int e   = t & 31;
        int j16 = t >> 5;          // 0..15
        int cb  = j16 * 26;        // even; pairs never straddle the pos/RBF split
        const float* dle = Dl[e];
        _Float16* ah = &Ah[e * ASTRIDE];
        _Float16* al = &Al[e * ASTRIDE];
        int dpos = s_d[e];
#pragma unroll
        for (int q = 0; q < 13; q++) {
            int c = cb + 2 * q;
            float g0, g1;
            if (c < 16) {
                g0 = W_pos[dpos * 16 + c]     + b_pos[c];
                g1 = W_pos[dpos * 16 + c + 1] + b_pos[c + 1];
            } else {
                int cr = c - 16;
                int p  = cr >> 4;
                int r  = cr & 15;
                float D = dle[p];
                float mu0 = 2.0f + (float)r * (20.0f / 15.0f);
                float t0 = (D - mu0) * 0.8f;
                float t1 = (D - (mu0 + 20.0f / 15.0f)) * 0.8f;
                g0 = __expf(-t0 * t0);
                g1 = __expf(-t1 * t1);
            }
            float h0 = (float)(_Float16)g0, h1 = (float)(_Float16)g1;
            *(unsigned*)&ah[c] = pack2h(g0, g1);
            *(unsigned*)&al[c] = pack2h(g0 - h0, g1 - h1);
        }
    }
    __syncthreads();

    // --- MFMA GEMM: 32x416 x 416x128 -> fp32, split precision ---
    int lane  = t & 63;
    int w     = t >> 6;
    int strip = (w >> 2) * 16;     // edge strip base
    int cq    = w & 3;             // feature quad: n in [cq*32, cq*32+32)
    int m     = lane & 15;
    int quad  = lane >> 4;
    const _Float16* pah = &Ah[(strip + m) * ASTRIDE + quad * 8];
    const _Float16* pal = &Al[(strip + m) * ASTRIDE + quad * 8];

    floatx4 acc[2];
    acc[0] = (floatx4){0.f, 0.f, 0.f, 0.f};
    acc[1] = (floatx4){0.f, 0.f, 0.f, 0.f};

    half8 bh[2], bl[2], bnh[2], bnl[2];
#pragma unroll
    for (int c = 0; c < 2; c++) {
        int idx = (cq * 2 + c) * 64 + lane;
        bh[c] = Wfh[idx];
        bl[c] = Wfl[idx];
    }

#pragma unroll 1
    for (int kk = 0; kk < KT; kk++) {
        half8 a_hi = *(const half8*)(pah + kk * 32);
        half8 a_lo = *(const half8*)(pal + kk * 32);
        if (kk < KT - 1) {
#pragma unroll
            for (int c = 0; c < 2; c++) {
                int idx = ((kk + 1) * 8 + cq * 2 + c) * 64 + lane;
                bnh[c] = Wfh[idx];
                bnl[c] = Wfl[idx];
            }
        }
#pragma unroll
        for (int c = 0; c < 2; c++) {
            acc[c] = __builtin_amdgcn_mfma_f32_16x16x32_f16(a_hi, bh[c], acc[c], 0, 0, 0);
            acc[c] = __builtin_amdgcn_mfma_f32_16x16x32_f16(a_lo, bh[c], acc[c], 0, 0, 0);
            acc[c] = __builtin_amdgcn_mfma_f32_16x16x32_f16(a_hi, bl[c], acc[c], 0, 0, 0);
        }
#pragma unroll
        for (int c = 0; c < 2; c++) { bh[c] = bnh[c]; bl[c] = bnl[c]; }
    }

    // --- LayerNorm epilogue: features of one edge split across the 4 cq waves ---
    // D[row = quad*4 + r][col = m]; edge_local = strip + quad*4 + r.
    int elb = strip + quad * 4;
    float sarr[4];
#pragma unroll
    for (int r = 0; r < 4; r++) {
        float s = acc[0][r] + acc[1][r];
        for (int msk = 1; msk <= 8; msk <<= 1) s += __shfl_xor(s, msk);
        sarr[r] = s;                       // this wave's 32-feature partial
    }
    if (m == 0) {
#pragma unroll
        for (int r = 0; r < 4; r++) redS[cq][elb + r] = sarr[r];
    }
    __syncthreads();
    float dvv[2][4];
#pragma unroll
    for (int r = 0; r < 4; r++) {
        float mu = (redS[0][elb + r] + redS[1][elb + r] +
                    redS[2][elb + r] + redS[3][elb + r]) * (1.0f / 128.0f);
        float v = 0.f;
#pragma unroll
        for (int c = 0; c < 2; c++) { dvv[c][r] = acc[c][r] - mu; v += dvv[c][r] * dvv[c][r]; }
        for (int msk = 1; msk <= 8; msk <<= 1) v += __shfl_xor(v, msk);
        if (m == 0) redT[cq][elb + r] = v;
    }
    __syncthreads();
#pragma unroll
    for (int r = 0; r < 4; r++) {
        float var  = (redT[0][elb + r] + redT[1][elb + r] +
                      redT[2][elb + r] + redT[3][elb + r]) * (1.0f / 128.0f);
        float rstd = rsqrtf(var + 1e-5f);
        int e = e0 + elb + r;
        float* orow = out + (size_t)e * 128;
#pragma unroll
        for (int c = 0; c < 2; c++) {
            int n = (cq * 2 + c) * 16 + m;
            orow[n] = dvv[c][r] * rstd * gamma[n] + beta[n];
        }
    }
}

// ---------------------------------------------------------------------------
extern "C" void kernel_launch(void* const* d_in, const int* in_sizes, int n_in,
                              void* d_out, int out_size, void* d_ws, size_t ws_size,
                              hipStream_t stream) {
    const float* X      = (const float*)d_in[0];
    const float* mask   = (const float*)d_in[1];
    const int*   resi   = (const int*)  d_in[2];
    const float* W_pos  = (const float*)d_in[3];
    const float* b_pos  = (const float*)d_in[4];
    const float* W_edge = (const float*)d_in[5];
    const float* gamma  = (const float*)d_in[6];
    const float* beta   = (const float*)d_in[7];
    float* out = (float*)d_out;

    float* atoms = (float*)d_ws;                                     // 491520 B
    int*   E_idx = (int*)((char*)d_ws + (size_t)NRES * 15 * 4);      // 983040 B
    half8* Wfh   = (half8*)((char*)d_ws + 1474560);                  // 106496 B
    half8* Wfl   = (half8*)((char*)d_ws + 1581056);                  // 106496 B

    atoms_kernel<<<(NRES + 255) / 256, 256, 0, stream>>>(X, atoms);
    wprep_kernel<<<(KT * 8 * 64 + 255) / 256, 256, 0, stream>>>(W_edge, Wfh, Wfl);
    topk_kernel<<<NRES / 4, 256, 0, stream>>>(X, mask, E_idx);
    edge_kernel<<<NEDGE / ME, 512, 0, stream>>>(atoms, E_idx, resi,
                                                W_pos, b_pos, Wfh, Wfl, gamma, beta, out);
}